// Round 1
// baseline (173.489 us; speedup 1.0000x reference)
//
#include <hip/hip_runtime.h>

#define WIDTH 16
#define NH 8

__device__ __forceinline__ float fast_tanh(float v) {
    // tanh(x) = 1 - 2/(e^{2x}+1);  e^{2x} = 2^{x * 2*log2(e)}
    float e = __builtin_amdgcn_exp2f(v * 2.8853900817779268f);
    return 1.0f - 2.0f * __builtin_amdgcn_rcpf(e + 1.0f);
}

__global__ __launch_bounds__(256) void cppn_kernel(
    const float* __restrict__ x,
    const float* __restrict__ W0,
    const float* __restrict__ b0,
    const float* __restrict__ Wh,
    const float* __restrict__ bh,
    const float* __restrict__ Wo,
    const float* __restrict__ bo,
    float* __restrict__ out, int n)
{
    int i = blockIdx.x * blockDim.x + threadIdx.x;
    if (i >= n) return;

    float x0 = x[i * 3 + 0];
    float x1 = x[i * 3 + 1];
    float x2 = x[i * 3 + 2];

    float h[WIDTH];
    #pragma unroll
    for (int j = 0; j < WIDTH; ++j) {
        float a = b0[j]
                + W0[j * 3 + 0] * x0
                + W0[j * 3 + 1] * x1
                + W0[j * 3 + 2] * x2;
        h[j] = fast_tanh(a);
    }

    for (int l = 0; l < NH; ++l) {
        const float* __restrict__ w = Wh + l * WIDTH * WIDTH;
        const float* __restrict__ b = bh + l * WIDTH;
        float hn[WIDTH];
        #pragma unroll
        for (int j = 0; j < WIDTH; ++j) {
            float a = b[j];
            #pragma unroll
            for (int k = 0; k < WIDTH; ++k)
                a = fmaf(w[j * WIDTH + k], h[k], a);
            hn[j] = fast_tanh(a);
        }
        #pragma unroll
        for (int j = 0; j < WIDTH; ++j) h[j] = hn[j];
    }

    float a = bo[0];
    #pragma unroll
    for (int k = 0; k < WIDTH; ++k)
        a = fmaf(Wo[k], h[k], a);

    // sigmoid(a) = 1/(1 + e^{-a})
    float e = __builtin_amdgcn_exp2f(-a * 1.4426950408889634f);
    out[i] = __builtin_amdgcn_rcpf(1.0f + e);
}

extern "C" void kernel_launch(void* const* d_in, const int* in_sizes, int n_in,
                              void* d_out, int out_size, void* d_ws, size_t ws_size,
                              hipStream_t stream) {
    const float* x  = (const float*)d_in[0];
    const float* W0 = (const float*)d_in[1];
    const float* b0 = (const float*)d_in[2];
    const float* Wh = (const float*)d_in[3];
    const float* bh = (const float*)d_in[4];
    const float* Wo = (const float*)d_in[5];
    const float* bo = (const float*)d_in[6];
    float* out = (float*)d_out;

    int n = out_size;  // 2097152 points
    int block = 256;
    int grid = (n + block - 1) / block;
    cppn_kernel<<<grid, block, 0, stream>>>(x, W0, b0, Wh, bh, Wo, bo, out, n);
}

// Round 3
// 119.112 us; speedup vs baseline: 1.4565x; 1.4565x over previous
//
#include <hip/hip_runtime.h>

typedef __attribute__((ext_vector_type(4))) _Float16 half4;
typedef __attribute__((ext_vector_type(4))) float floatx4;

#define NH 8

__device__ __forceinline__ float fast_tanh(float v) {
    // tanh(x) = 1 - 2/(e^{2x}+1);  e^{2x} = 2^(x * 2*log2(e))
    float e = __builtin_amdgcn_exp2f(v * 2.8853900817779268f);
    return 1.0f - 2.0f * __builtin_amdgcn_rcpf(e + 1.0f);
}

__global__ __launch_bounds__(256) void cppn_kernel(
    const float* __restrict__ x,
    const float* __restrict__ W0,
    const float* __restrict__ b0,
    const float* __restrict__ Wh,
    const float* __restrict__ bh,
    const float* __restrict__ Wo,
    const float* __restrict__ bo,
    float* __restrict__ out, int n)
{
    const int tid  = threadIdx.x;
    const int lane = tid & 63;
    const int col  = lane & 15;   // MFMA j (point within tile) / A row i
    const int kg   = lane >> 4;   // k-group 0..3
    const int waveInBlock = tid >> 6;
    const long base = ((long)blockIdx.x * 4 + waveInBlock) * 64;  // 64 pts/wave
    if (base >= n) return;

    const float LO_SCALE   = 2048.0f;        // 2^11 keeps lo terms f16-normal
    const float LO_UNSCALE = 4.8828125e-4f;  // 2^-11

    // ---- preload hidden weights as split f16 A-fragments + f32 bias C ----
    // A[i=fo][k=fi]: lane holds i=col, k=kg*4+r  -> Wh[l][col][kg*4+r]
    // C/D[i][j=pt]:  lane holds i=kg*4+r, j=col  -> bias bh[l][kg*4+r]
    half4   wAhi[NH], wAlo[NH];
    floatx4 bC[NH];
    #pragma unroll
    for (int l = 0; l < NH; ++l) {
        const float* wrow = Wh + l*256 + col*16 + kg*4;
        half4 ahi, alo;
        #pragma unroll
        for (int r = 0; r < 4; ++r) {
            float w = wrow[r];
            _Float16 hi = (_Float16)w;                      // RNE
            ahi[r] = hi;
            alo[r] = (_Float16)((w - (float)hi) * LO_SCALE);
        }
        wAhi[l] = ahi; wAlo[l] = alo;
        const float* bp = bh + l*16 + kg*4;
        floatx4 c; c[0]=bp[0]; c[1]=bp[1]; c[2]=bp[2]; c[3]=bp[3];
        bC[l] = c;
    }

    // input layer weights: rows k = kg*4+r (feed B-fragment layout directly)
    float w0r[4][3]; float b0r[4];
    #pragma unroll
    for (int r = 0; r < 4; ++r) {
        const float* wp = W0 + (kg*4 + r)*3;
        w0r[r][0] = wp[0]; w0r[r][1] = wp[1]; w0r[r][2] = wp[2];
        b0r[r] = b0[kg*4 + r];
    }

    // output layer weights
    float wo[4];
    { const float* wp = Wo + kg*4;
      wo[0]=wp[0]; wo[1]=wp[1]; wo[2]=wp[2]; wo[3]=wp[3]; }
    const float bov = bo[0];

    // ---- input layer -> split B-fragments H0 for 4 tiles of 16 points ----
    half4 hBhi[4], hBlo[4];
    #pragma unroll
    for (int t = 0; t < 4; ++t) {
        long p = base + t*16 + col;
        if (p >= n) p = n - 1;
        float x0 = x[p*3+0], x1 = x[p*3+1], x2 = x[p*3+2];
        half4 bhi, blo;
        #pragma unroll
        for (int r = 0; r < 4; ++r) {
            float a = fmaf(w0r[r][0], x0,
                      fmaf(w0r[r][1], x1,
                      fmaf(w0r[r][2], x2, b0r[r])));
            float t32 = fast_tanh(a);
            _Float16 hi = (_Float16)t32;
            bhi[r] = hi;
            blo[r] = (_Float16)((t32 - (float)hi) * LO_SCALE);
        }
        hBhi[t] = bhi; hBlo[t] = blo;
    }

    const floatx4 zeroC = {0.0f, 0.0f, 0.0f, 0.0f};

    // ---- hidden layers 0..6: split-precision MFMA, tanh, re-split ----
    #pragma unroll
    for (int l = 0; l < NH-1; ++l) {
        floatx4 d[4], e[4];
        #pragma unroll
        for (int t = 0; t < 4; ++t) {
            d[t] = __builtin_amdgcn_mfma_f32_16x16x16f16(wAhi[l], hBhi[t], bC[l], 0,0,0);
            e[t] = __builtin_amdgcn_mfma_f32_16x16x16f16(wAhi[l], hBlo[t], zeroC, 0,0,0);
            e[t] = __builtin_amdgcn_mfma_f32_16x16x16f16(wAlo[l], hBhi[t], e[t], 0,0,0);
        }
        #pragma unroll
        for (int t = 0; t < 4; ++t) {
            half4 bhi, blo;
            #pragma unroll
            for (int r = 0; r < 4; ++r) {
                float a = fmaf(e[t][r], LO_UNSCALE, d[t][r]);
                float t32 = fast_tanh(a);
                _Float16 hi = (_Float16)t32;
                bhi[r] = hi;
                blo[r] = (_Float16)((t32 - (float)hi) * LO_SCALE);
            }
            hBhi[t] = bhi; hBlo[t] = blo;
        }
    }

    // ---- last hidden layer: f32 tanh feeds the output dot directly ----
    floatx4 dd[4];
    #pragma unroll
    for (int t = 0; t < 4; ++t) {
        floatx4 d = __builtin_amdgcn_mfma_f32_16x16x16f16(wAhi[NH-1], hBhi[t], bC[NH-1], 0,0,0);
        floatx4 e = __builtin_amdgcn_mfma_f32_16x16x16f16(wAhi[NH-1], hBlo[t], zeroC, 0,0,0);
        e = __builtin_amdgcn_mfma_f32_16x16x16f16(wAlo[NH-1], hBhi[t], e, 0,0,0);
        floatx4 m;
        #pragma unroll
        for (int r = 0; r < 4; ++r) m[r] = fmaf(e[r], LO_UNSCALE, d[r]);
        dd[t] = m;
    }

    float tot[4];
    #pragma unroll
    for (int t = 0; t < 4; ++t) {
        float s = 0.0f;
        #pragma unroll
        for (int r = 0; r < 4; ++r)
            s = fmaf(wo[r], fast_tanh(dd[t][r]), s);
        s += __shfl_xor(s, 16);
        s += __shfl_xor(s, 32);
        tot[t] = s;
    }

    // lane writes point of tile t = kg  ->  out[base + lane], coalesced
    float s = (kg == 0) ? tot[0] : (kg == 1) ? tot[1] : (kg == 2) ? tot[2] : tot[3];
    s += bov;
    float e = __builtin_amdgcn_exp2f(-s * 1.4426950408889634f);
    float val = __builtin_amdgcn_rcpf(1.0f + e);
    if (base + lane < n) out[base + lane] = val;
}

extern "C" void kernel_launch(void* const* d_in, const int* in_sizes, int n_in,
                              void* d_out, int out_size, void* d_ws, size_t ws_size,
                              hipStream_t stream) {
    const float* x  = (const float*)d_in[0];
    const float* W0 = (const float*)d_in[1];
    const float* b0 = (const float*)d_in[2];
    const float* Wh = (const float*)d_in[3];
    const float* bh = (const float*)d_in[4];
    const float* Wo = (const float*)d_in[5];
    const float* bo = (const float*)d_in[6];
    float* out = (float*)d_out;

    int n = out_size;                       // 2097152 points
    int block = 256;                        // 4 waves * 64 pts
    int grid = (n + block - 1) / block;
    cppn_kernel<<<grid, block, 0, stream>>>(x, W0, b0, Wh, bh, Wo, bo, out, n);
}

// Round 6
// 118.606 us; speedup vs baseline: 1.4627x; 1.0043x over previous
//
#include <hip/hip_runtime.h>

typedef __attribute__((ext_vector_type(4))) _Float16 half4;
typedef __attribute__((ext_vector_type(4))) float floatx4;
typedef __attribute__((ext_vector_type(2))) unsigned uint2v;

#define NH 8
#define CHUNKS 4

// round-half-up to 10-bit mantissa: result is exactly f16-representable,
// |t - rhu10(t)| <= 0.5 ulp(f16). Works on sign-magnitude f32 for +/-.
__device__ __forceinline__ float rhu10(float t) {
    unsigned u = __builtin_bit_cast(unsigned, t);
    u = (u + 0x1000u) & 0xFFFFE000u;
    return __builtin_bit_cast(float, u);
}

struct Split2 { unsigned hi, lo; };

// s is pre-scaled by 2*log2(e): tanh(a) = 1 - 2/(2^s + 1), s = 2*log2e*a.
// Saturates safely: s>~128 -> E=inf -> rcp=0 -> t=1; s<<0 -> E=0 -> t=-1.
__device__ __forceinline__ Split2 tanh_split2(float s0, float s1) {
    float E0 = __builtin_amdgcn_exp2f(s0);
    float E1 = __builtin_amdgcn_exp2f(s1);
    float r0 = __builtin_amdgcn_rcpf(E0 + 1.0f);
    float r1 = __builtin_amdgcn_rcpf(E1 + 1.0f);
    float t0 = fmaf(-2.0f, r0, 1.0f);
    float t1 = fmaf(-2.0f, r1, 1.0f);
    float h0 = rhu10(t0), h1 = rhu10(t1);
    float l0 = (t0 - h0) * 2048.0f;       // exact residual, f16-normal range
    float l1 = (t1 - h1) * 2048.0f;
    Split2 r;
    r.hi = __builtin_bit_cast(unsigned, __builtin_amdgcn_cvt_pkrtz(h0, h1)); // exact
    r.lo = __builtin_bit_cast(unsigned, __builtin_amdgcn_cvt_pkrtz(l0, l1));
    return r;
}

__device__ __forceinline__ void split_w(float w, float& hi, float& lo) {
    _Float16 h = (_Float16)w;             // RNE
    hi = (float)h;
    lo = (w - hi) * 2048.0f;
}

__global__ __launch_bounds__(256) void cppn_kernel(
    const float* __restrict__ x,
    const float* __restrict__ W0,
    const float* __restrict__ b0,
    const float* __restrict__ Wh,
    const float* __restrict__ bh,
    const float* __restrict__ Wo,
    const float* __restrict__ bo,
    float* __restrict__ out, int n)
{
    const int tid  = threadIdx.x;
    const int lane = tid & 63;
    const int col  = lane & 15;   // MFMA j (point within tile) / A row i
    const int kg   = lane >> 4;   // k-group 0..3
    const int wib  = tid >> 6;
    const long base0 = ((long)blockIdx.x * 4 + wib) * (64L * CHUNKS);
    if (base0 >= n) return;

    const float TSCL = 2.8853900817779268f;   // 2*log2(e): tanh pre-scale
    const float OSCL = -1.4426950408889634f;  // -log2(e): sigmoid pre-scale
    const float UNSC = 4.8828125e-4f;         // 2^-11

    // ---- preload hidden weights (scaled, RNE hi/lo split) + scaled bias ----
    // A[i=fo][k=fi]: lane holds i=col, k=kg*4+r  -> Wh[l][col][kg*4+r]
    // C/D[i][j=pt]:  lane holds i=kg*4+r, j=col  -> bias bh[l][kg*4+r]
    half4   wAhi[NH], wAlo[NH];
    floatx4 bC[NH];
    #pragma unroll
    for (int l = 0; l < NH; ++l) {
        const float* wrow = Wh + l*256 + col*16 + kg*4;
        float h0,h1,h2,h3, lo0,lo1,lo2,lo3;
        split_w(wrow[0]*TSCL, h0, lo0);
        split_w(wrow[1]*TSCL, h1, lo1);
        split_w(wrow[2]*TSCL, h2, lo2);
        split_w(wrow[3]*TSCL, h3, lo3);
        uint2v ha, la;
        ha.x = __builtin_bit_cast(unsigned, __builtin_amdgcn_cvt_pkrtz(h0, h1)); // exact
        ha.y = __builtin_bit_cast(unsigned, __builtin_amdgcn_cvt_pkrtz(h2, h3));
        la.x = __builtin_bit_cast(unsigned, __builtin_amdgcn_cvt_pkrtz(lo0, lo1));
        la.y = __builtin_bit_cast(unsigned, __builtin_amdgcn_cvt_pkrtz(lo2, lo3));
        wAhi[l] = __builtin_bit_cast(half4, ha);
        wAlo[l] = __builtin_bit_cast(half4, la);
        const float* bp = bh + l*16 + kg*4;
        floatx4 c; c[0]=bp[0]*TSCL; c[1]=bp[1]*TSCL; c[2]=bp[2]*TSCL; c[3]=bp[3]*TSCL;
        bC[l] = c;
    }

    // input layer (rows k = kg*4+r feed B-fragment layout directly), scaled
    float w0r[4][3]; float b0r[4];
    #pragma unroll
    for (int r = 0; r < 4; ++r) {
        const float* wp = W0 + (kg*4 + r)*3;
        w0r[r][0] = wp[0]*TSCL; w0r[r][1] = wp[1]*TSCL; w0r[r][2] = wp[2]*TSCL;
        b0r[r] = b0[kg*4 + r]*TSCL;
    }

    // output layer, sigmoid scale folded (negated)
    float wo2[4];
    { const float* wp = Wo + kg*4;
      wo2[0]=wp[0]*OSCL; wo2[1]=wp[1]*OSCL; wo2[2]=wp[2]*OSCL; wo2[3]=wp[3]*OSCL; }
    const float bo2 = bo[0]*OSCL;

    const floatx4 zeroC = {0.0f, 0.0f, 0.0f, 0.0f};

    // x prefetch for chunk 0
    float xs[4][3];
    #pragma unroll
    for (int t = 0; t < 4; ++t) {
        long p = base0 + t*16 + col; if (p >= n) p = n - 1;
        xs[t][0]=x[p*3+0]; xs[t][1]=x[p*3+1]; xs[t][2]=x[p*3+2];
    }

    #pragma unroll 1
    for (int c = 0; c < CHUNKS; ++c) {
        const long base = base0 + (long)c * 64;

        // prefetch next chunk's x (clamped; last iteration re-reads valid mem)
        float xn[4][3];
        #pragma unroll
        for (int t = 0; t < 4; ++t) {
            long p = base + 64 + t*16 + col; if (p >= n) p = n - 1;
            xn[t][0]=x[p*3+0]; xn[t][1]=x[p*3+1]; xn[t][2]=x[p*3+2];
        }

        // ---- input layer -> split B-fragments ----
        half4 hBhi[4], hBlo[4];
        #pragma unroll
        for (int t = 0; t < 4; ++t) {
            float a[4];
            #pragma unroll
            for (int r = 0; r < 4; ++r)
                a[r] = fmaf(w0r[r][0], xs[t][0],
                       fmaf(w0r[r][1], xs[t][1],
                       fmaf(w0r[r][2], xs[t][2], b0r[r])));
            Split2 p01 = tanh_split2(a[0], a[1]);
            Split2 p23 = tanh_split2(a[2], a[3]);
            uint2v hb, lb;
            hb.x = p01.hi; hb.y = p23.hi;
            lb.x = p01.lo; lb.y = p23.lo;
            hBhi[t] = __builtin_bit_cast(half4, hb);
            hBlo[t] = __builtin_bit_cast(half4, lb);
        }

        // ---- hidden layers 0..6: split-precision MFMA + fused tanh/split ----
        #pragma unroll
        for (int l = 0; l < NH-1; ++l) {
            floatx4 d[4], e[4];
            #pragma unroll
            for (int t = 0; t < 4; ++t) {
                d[t] = __builtin_amdgcn_mfma_f32_16x16x16f16(wAhi[l], hBhi[t], bC[l], 0,0,0);
                e[t] = __builtin_amdgcn_mfma_f32_16x16x16f16(wAhi[l], hBlo[t], zeroC, 0,0,0);
                e[t] = __builtin_amdgcn_mfma_f32_16x16x16f16(wAlo[l], hBhi[t], e[t], 0,0,0);
            }
            #pragma unroll
            for (int t = 0; t < 4; ++t) {
                float s0 = fmaf(e[t][0], UNSC, d[t][0]);
                float s1 = fmaf(e[t][1], UNSC, d[t][1]);
                float s2 = fmaf(e[t][2], UNSC, d[t][2]);
                float s3 = fmaf(e[t][3], UNSC, d[t][3]);
                Split2 p01 = tanh_split2(s0, s1);
                Split2 p23 = tanh_split2(s2, s3);
                uint2v hb, lb;
                hb.x = p01.hi; hb.y = p23.hi;
                lb.x = p01.lo; lb.y = p23.lo;
                hBhi[t] = __builtin_bit_cast(half4, hb);
                hBlo[t] = __builtin_bit_cast(half4, lb);
            }
        }

        // ---- last hidden layer + output dot + sigmoid ----
        float tot[4];
        #pragma unroll
        for (int t = 0; t < 4; ++t) {
            floatx4 d = __builtin_amdgcn_mfma_f32_16x16x16f16(wAhi[NH-1], hBhi[t], bC[NH-1], 0,0,0);
            floatx4 e = __builtin_amdgcn_mfma_f32_16x16x16f16(wAhi[NH-1], hBlo[t], zeroC, 0,0,0);
            e = __builtin_amdgcn_mfma_f32_16x16x16f16(wAlo[NH-1], hBhi[t], e, 0,0,0);
            float acc = 0.0f;
            #pragma unroll
            for (int r = 0; r < 4; ++r) {
                float sv = fmaf(e[r], UNSC, d[r]);
                float E = __builtin_amdgcn_exp2f(sv);
                float rc = __builtin_amdgcn_rcpf(E + 1.0f);
                float tt = fmaf(-2.0f, rc, 1.0f);
                acc = fmaf(wo2[r], tt, acc);
            }
            acc += __shfl_xor(acc, 16);
            acc += __shfl_xor(acc, 32);
            tot[t] = acc;
        }

        float s = (kg == 0) ? tot[0] : (kg == 1) ? tot[1] : (kg == 2) ? tot[2] : tot[3];
        s += bo2;
        float E = __builtin_amdgcn_exp2f(s);
        float val = __builtin_amdgcn_rcpf(1.0f + E);
        if (base + lane < n) out[base + lane] = val;

        #pragma unroll
        for (int t = 0; t < 4; ++t) {
            xs[t][0]=xn[t][0]; xs[t][1]=xn[t][1]; xs[t][2]=xn[t][2];
        }
    }
}

extern "C" void kernel_launch(void* const* d_in, const int* in_sizes, int n_in,
                              void* d_out, int out_size, void* d_ws, size_t ws_size,
                              hipStream_t stream) {
    const float* x  = (const float*)d_in[0];
    const float* W0 = (const float*)d_in[1];
    const float* b0 = (const float*)d_in[2];
    const float* Wh = (const float*)d_in[3];
    const float* bh = (const float*)d_in[4];
    const float* Wo = (const float*)d_in[5];
    const float* bo = (const float*)d_in[6];
    float* out = (float*)d_out;

    int n = out_size;                           // 2097152 points
    int block = 256;                            // 4 waves
    long ptsPerBlock = 4L * 64 * CHUNKS;        // 1024
    int grid = (int)((n + ptsPerBlock - 1) / ptsPerBlock);
    cppn_kernel<<<grid, block, 0, stream>>>(x, W0, b0, Wh, bh, Wo, bo, out, n);
}